// Round 12
// baseline (28.464 us; speedup 1.0000x reference)
//
#include <hip/hip_runtime.h>
#include <hip/hip_bf16.h>

#define DD 256
#define SS 128
#define BB 16

typedef __attribute__((ext_vector_type(8))) short bf16x8;
typedef __attribute__((ext_vector_type(4))) float f32x4;

static __device__ __forceinline__ short f2bf(float f) {
    __hip_bfloat16 h = __float2bfloat16(f);
    return *reinterpret_cast<short*>(&h);
}

// async global->LDS, 16B per lane, LDS dest = wave-uniform base + lane*16
static __device__ __forceinline__ void gl_lds16(const float* g, float* l) {
    __builtin_amdgcn_global_load_lds(
        (const __attribute__((address_space(1))) void*)g,
        (__attribute__((address_space(3))) void*)l,
        16, 0, 0);
}

// ws layout (floats): sumLg [B][D], sumRg [B][D], absS [B][D]

// ---------------- fused: async gather + projection (MFMA) + all-pairs ----------------
// grid 256 = B(16) x 16 d-chunks; 512 threads = 8 waves; 1 block/CU (147.5 KB LDS).
__global__ __launch_bounds__(512) void k_fused(
    const int* __restrict__ X, const float* __restrict__ emb,
    const float* __restrict__ Wl, const float* __restrict__ bl,
    const float* __restrict__ Wr, const float* __restrict__ br,
    float* __restrict__ sumLg, float* __restrict__ sumRg,
    float* __restrict__ absS)
{
    __shared__ __align__(16) float Ef[128 * 256];     // 128 KB f32, chunk-XOR swizzled
    __shared__ __align__(16) float Lcol[16 * 132];    // [d][s]
    __shared__ __align__(16) float Rcol[16 * 132];
    __shared__ float redA[512];
    __shared__ float redwL[8 * 16];
    __shared__ float redwR[8 * 16];

    const int tid  = threadIdx.x;
    // XCD-bijective swizzle: 32 consecutive logical blocks (2 batches) per XCD
    const int bx   = (blockIdx.x & 7) * 32 + (blockIdx.x >> 3);
    const int b    = bx >> 4;
    const int dc   = bx & 15;
    const int dr0  = dc * 16;
    const int w    = tid >> 6;          // wave 0..7 -> token rows w*16..w*16+15
    const int lane = tid & 63;
    const int lr   = lane & 15, lk = lane >> 4;

    // ---- async gather: wave w issues all 16 of its emb rows, VGPR-free ----
    // LDS chunk l of row r holds global chunk (l ^ (r&7)) (16B chunks):
    // pre-swizzled global address, linear LDS dest (global_load_lds constraint).
#pragma unroll
    for (int i = 0; i < 16; ++i) {
        const int r   = w * 16 + i;                  // wave-uniform
        const int tok = X[b * SS + r];               // wave-uniform -> s_load
        const float* g = emb + (size_t)tok * DD + ((lane ^ (r & 7)) << 2);
        gl_lds16(g, &Ef[r * 256]);
    }

    // ---- W fragments: f32 -> bf16 in registers (overlaps gather flight) ----
    bf16x8 wlf[8], wrf[8];
    {
        const float* plw = Wl + (size_t)(dr0 + lr) * DD + lk * 8;
        const float* prw = Wr + (size_t)(dr0 + lr) * DD + lk * 8;
#pragma unroll
        for (int ks = 0; ks < 8; ++ks) {
            float4 f0 = *(const float4*)(plw + ks * 32);
            float4 f1 = *(const float4*)(plw + ks * 32 + 4);
            bf16x8 p;
            p[0]=f2bf(f0.x); p[1]=f2bf(f0.y); p[2]=f2bf(f0.z); p[3]=f2bf(f0.w);
            p[4]=f2bf(f1.x); p[5]=f2bf(f1.y); p[6]=f2bf(f1.z); p[7]=f2bf(f1.w);
            wlf[ks] = p;
            f0 = *(const float4*)(prw + ks * 32);
            f1 = *(const float4*)(prw + ks * 32 + 4);
            p[0]=f2bf(f0.x); p[1]=f2bf(f0.y); p[2]=f2bf(f0.z); p[3]=f2bf(f0.w);
            p[4]=f2bf(f1.x); p[5]=f2bf(f1.y); p[6]=f2bf(f1.z); p[7]=f2bf(f1.w);
            wrf[ks] = p;
        }
    }

    // drain gather (and W loads). No barrier: each wave reads only its own rows.
    asm volatile("s_waitcnt vmcnt(0)" ::: "memory");

    // ---- MFMA: wave w -> tokens w*16..w*16+15, 16 d's; A-frag from f32 LDS ----
    f32x4 accL = {0.f,0.f,0.f,0.f}, accR = accL;
    const float* Erow = &Ef[(size_t)(w * 16 + lr) * 256];
    const int xw = lr & 7;
#pragma unroll
    for (int ks = 0; ks < 8; ++ks) {
        const int c0 = ks * 8 + lk * 2;
        float4 fa = *(const float4*)&Erow[(c0 ^ xw) << 2];
        float4 fb = *(const float4*)&Erow[((c0 + 1) ^ xw) << 2];
        bf16x8 a;
        a[0]=f2bf(fa.x); a[1]=f2bf(fa.y); a[2]=f2bf(fa.z); a[3]=f2bf(fa.w);
        a[4]=f2bf(fb.x); a[5]=f2bf(fb.y); a[6]=f2bf(fb.z); a[7]=f2bf(fb.w);
        accL = __builtin_amdgcn_mfma_f32_16x16x32_bf16(a, wlf[ks], accL, 0, 0, 0);
        accR = __builtin_amdgcn_mfma_f32_16x16x32_bf16(a, wrf[ks], accR, 0, 0, 0);
    }
    const float blv = bl[dr0 + lr];
    const float brv = br[dr0 + lr];
    // C mapping (m89-verified): col = lane&15 (d), row = (lane>>4)*4 + reg (token)
#pragma unroll
    for (int reg = 0; reg < 4; ++reg) {
        int s = w * 16 + lk * 4 + reg;
        Lcol[lr * 132 + s] = accL[reg] + blv;
        Rcol[lr * 132 + s] = accR[reg] + brv;
    }
    float tl = (accL[0] + accL[1]) + (accL[2] + accL[3]) + blv * 4.0f;
    float tr = (accR[0] + accR[1]) + (accR[2] + accR[3]) + brv * 4.0f;
    tl += __shfl_xor(tl, 16);  tr += __shfl_xor(tr, 16);
    tl += __shfl_xor(tl, 32);  tr += __shfl_xor(tr, 32);
    if (lane < 16) { redwL[w * 16 + lr] = tl; redwR[w * 16 + lr] = tr; }
    __syncthreads();

    // ---- all-pairs |L_i + R_j|: thread (d, jg) does 4 j's x 128 i's ----
    const int d = tid & 15, jg = tid >> 4;
    float rr[4];
    *(float4*)rr = *(float4*)&Rcol[d * 132 + jg * 4];

    float a0 = 0.f, a1 = 0.f, a2 = 0.f, a3 = 0.f;
    for (int i = 0; i < 128; i += 4) {
        float4 l4 = *(float4*)&Lcol[d * 132 + i];
#pragma unroll
        for (int q = 0; q < 4; ++q) {
            a0 += fabsf(l4.x + rr[q]);
            a1 += fabsf(l4.y + rr[q]);
            a2 += fabsf(l4.z + rr[q]);
            a3 += fabsf(l4.w + rr[q]);
        }
    }
    redA[tid] = (a0 + a1) + (a2 + a3);
    __syncthreads();

    if (tid < 16) {
        float sa = 0.f;
#pragma unroll
        for (int g = 0; g < 32; ++g) sa += redA[g * 16 + tid];
        float sl = 0.f, sr = 0.f;
#pragma unroll
        for (int wv = 0; wv < 8; ++wv) {
            sl += redwL[wv * 16 + tid];
            sr += redwR[wv * 16 + tid];
        }
        absS [b * DD + dr0 + tid] = sa;
        sumLg[b * DD + dr0 + tid] = sl;
        sumRg[b * DD + dr0 + tid] = sr;
    }
}

// ---------------- final: pooled affine, 4-way split-K (depth ~1) ----------------
// grid 16 = B; 1024 threads = 256 rows x 4 k-quarters; 16 Wrel loads in flight.
__global__ __launch_bounds__(1024) void k_final(
    const float* __restrict__ sumLg, const float* __restrict__ sumRg,
    const float* __restrict__ absS,
    const float* __restrict__ Wrel, const float* __restrict__ brel,
    float* __restrict__ out)
{
    __shared__ float plds[DD];
    __shared__ float part[4][256];
    const int tid = threadIdx.x;
    const int b   = blockIdx.x;
    const int row = tid & 255, q = tid >> 8;

    if (tid < DD) {
        float sl = sumLg[b * DD + tid];
        float sr = sumRg[b * DD + tid];
        float sa = absS [b * DD + tid];
        // pooled = (S*(sumL+sumR) + sumAbs) / (2*S*S)
        plds[tid] = (128.0f * (sl + sr) + sa) * (1.0f / 32768.0f);
    }

    // issue all 16 Wrel float4 loads up front (independent of plds)
    const float4* w4 = (const float4*)(Wrel + (size_t)row * DD + q * 64);
    float4 wr[16];
#pragma unroll
    for (int i = 0; i < 16; ++i) wr[i] = w4[i];

    __syncthreads();

    float acc = 0.f;
#pragma unroll
    for (int i = 0; i < 16; ++i) {
        float4 p = *(float4*)&plds[q * 64 + i * 4];
        acc = fmaf(wr[i].x, p.x, acc);
        acc = fmaf(wr[i].y, p.y, acc);
        acc = fmaf(wr[i].z, p.z, acc);
        acc = fmaf(wr[i].w, p.w, acc);
    }
    part[q][row] = acc;
    __syncthreads();

    if (tid < 256)
        out[b * DD + tid] = brel[tid] +
            ((part[0][tid] + part[1][tid]) + (part[2][tid] + part[3][tid]));
}

extern "C" void kernel_launch(void* const* d_in, const int* in_sizes, int n_in,
                              void* d_out, int out_size, void* d_ws, size_t ws_size,
                              hipStream_t stream) {
    const int*   X    = (const int*)d_in[0];
    const float* emb  = (const float*)d_in[1];
    const float* Wl   = (const float*)d_in[2];
    const float* bl   = (const float*)d_in[3];
    const float* Wr   = (const float*)d_in[4];
    const float* br   = (const float*)d_in[5];
    const float* Wrel = (const float*)d_in[6];
    const float* brel = (const float*)d_in[7];
    float* out = (float*)d_out;

    float* ws    = (float*)d_ws;
    float* sumLg = ws;                 // [B][D]
    float* sumRg = sumLg + BB * DD;    // [B][D]
    float* absS  = sumRg + BB * DD;    // [B][D]

    k_fused<<<BB * 16, 512, 0, stream>>>(X, emb, Wl, bl, Wr, br,
                                         sumLg, sumRg, absS);
    k_final<<<BB, 1024, 0, stream>>>(sumLg, sumRg, absS, Wrel, brel, out);
}